// Round 6
// baseline (365.324 us; speedup 1.0000x reference)
//
#include <hip/hip_runtime.h>
#include <hip/hip_bf16.h>

typedef __bf16 bf16x8 __attribute__((ext_vector_type(8)));
typedef _Float16 f16x4 __attribute__((ext_vector_type(4)));
typedef __fp16 fp16x2 __attribute__((ext_vector_type(2)));
typedef float f32x4 __attribute__((ext_vector_type(4)));
typedef unsigned short ushort_t;
typedef ushort_t ushort8 __attribute__((ext_vector_type(8)));

#define DIM 512
#define HEADS 8
#define HD 64
#define HWN 4096   // 64*64 queries per batch
#define KVN 1024   // 32*32 kv tokens per batch
#define KKV 2048   // 512*2*2 im2col K for the strided conv
#define LOG2E 1.44269504f

__device__ __forceinline__ ushort_t f2bf(float f) {
    union { float f; unsigned u; } v; v.f = f;
    unsigned r = v.u + 0x7fffu + ((v.u >> 16) & 1u);
    return (ushort_t)(r >> 16);
}

// ---------------------------------------------------------------------------
// Kernel 0a: small f32 -> bf16 convert (wq, wout)
// ---------------------------------------------------------------------------
__global__ __launch_bounds__(256) void cvt_kernel(
        const float* __restrict__ src, ushort_t* __restrict__ dst, int n8) {
    int i = blockIdx.x * 256 + threadIdx.x;
    if (i >= n8) return;
    const float* p = &src[(size_t)i * 8];
    f32x4 v0 = *(const f32x4*)&p[0];
    f32x4 v1 = *(const f32x4*)&p[4];
    ushort8 w;
    w[0] = f2bf(v0[0]); w[1] = f2bf(v0[1]); w[2] = f2bf(v0[2]); w[3] = f2bf(v0[3]);
    w[4] = f2bf(v1[0]); w[5] = f2bf(v1[1]); w[6] = f2bf(v1[2]); w[7] = f2bf(v1[3]);
    *(ushort8*)&dst[i * 8] = w;
}

// ---------------------------------------------------------------------------
// Kernel 0b: x f32 [b][c][p] -> xT bf16 [b][p][c]   (tiled 64x64 transpose)
// ---------------------------------------------------------------------------
__global__ __launch_bounds__(256) void cvt_xT_kernel(
        const float* __restrict__ x, ushort_t* __restrict__ xT) {
    const int b  = blockIdx.z;
    const int c0 = blockIdx.y * 64;
    const int p0 = blockIdx.x * 64;
    __shared__ ushort_t tile[64 * 72];

    const int tid = threadIdx.x;
    {
        int r = tid >> 2, pc = (tid & 3) * 16;
        const float* src = &x[((size_t)b * DIM + c0 + r) * HWN + p0 + pc];
        f32x4 v0 = *(const f32x4*)&src[0];
        f32x4 v1 = *(const f32x4*)&src[4];
        f32x4 v2 = *(const f32x4*)&src[8];
        f32x4 v3 = *(const f32x4*)&src[12];
        ushort8 w0, w1;
        w0[0]=f2bf(v0[0]); w0[1]=f2bf(v0[1]); w0[2]=f2bf(v0[2]); w0[3]=f2bf(v0[3]);
        w0[4]=f2bf(v1[0]); w0[5]=f2bf(v1[1]); w0[6]=f2bf(v1[2]); w0[7]=f2bf(v1[3]);
        w1[0]=f2bf(v2[0]); w1[1]=f2bf(v2[1]); w1[2]=f2bf(v2[2]); w1[3]=f2bf(v2[3]);
        w1[4]=f2bf(v3[0]); w1[5]=f2bf(v3[1]); w1[6]=f2bf(v3[2]); w1[7]=f2bf(v3[3]);
        *(ushort8*)&tile[r * 72 + pc]     = w0;
        *(ushort8*)&tile[r * 72 + pc + 8] = w1;
    }
    __syncthreads();
    {
        int p = tid >> 2, cc = (tid & 3) * 16;
        ushort8 w0, w1;
        #pragma unroll
        for (int j = 0; j < 8; ++j) {
            w0[j] = tile[(cc + j) * 72 + p];
            w1[j] = tile[(cc + 8 + j) * 72 + p];
        }
        ushort_t* dst = &xT[((size_t)b * HWN + p0 + p) * DIM + c0 + cc];
        *(ushort8*)&dst[0] = w0;
        *(ushort8*)&dst[8] = w1;
    }
}

// ---------------------------------------------------------------------------
// Kernel 0c: wkv f32 [o2][c][di][dj] -> wkvT bf16 [o2][(di*2+dj)*512 + c]
// ---------------------------------------------------------------------------
__global__ __launch_bounds__(256) void cvt_wkvT_kernel(
        const float* __restrict__ wkv, ushort_t* __restrict__ wkvT) {
    int i = blockIdx.x * 256 + threadIdx.x;
    if (i >= 1024 * 512) return;
    int o2 = i >> 9, c = i & 511;
    f32x4 v = *(const f32x4*)&wkv[(size_t)i * 4];
    #pragma unroll
    for (int q = 0; q < 4; ++q)
        wkvT[(size_t)o2 * KKV + q * 512 + c] = f2bf(v[q]);
}

// ---------------------------------------------------------------------------
// Kernel 1: Q projection.  Qt[b][p][o] = 0.125 * sum_c Wq[o][c] * X[c][p]
// Token-major output (transpose epilogue) so attention reads Q B-frags
// as contiguous 16B loads.
// ---------------------------------------------------------------------------
__global__ __launch_bounds__(256) void qproj_kernel(
        const ushort_t* __restrict__ xT, const ushort_t* __restrict__ wqb,
        ushort_t* __restrict__ qt) {
    const int b  = blockIdx.z;
    const int m0 = blockIdx.y * 64;
    const int p0 = blockIdx.x * 64;

    __shared__ ushort_t ldsA[64 * 40];
    __shared__ ushort_t ldsB[64 * 40];
    __shared__ ushort_t cbuf[64 * 72];

    const int tid  = threadIdx.x;
    const int wave = tid >> 6;
    const int lane = tid & 63;
    const int l15  = lane & 15;
    const int quad = lane >> 4;
    const int mw   = (wave >> 1) * 32;
    const int nw   = (wave & 1) * 32;

    f32x4 zero = {0.f, 0.f, 0.f, 0.f};
    f32x4 acc[2][2] = {{zero, zero}, {zero, zero}};

    for (int k0 = 0; k0 < DIM; k0 += 32) {
        int row = tid >> 2, ko = (tid & 3) * 8;
        *(ushort8*)&ldsA[row * 40 + ko] =
            *(const ushort8*)&wqb[(m0 + row) * DIM + k0 + ko];
        *(ushort8*)&ldsB[row * 40 + ko] =
            *(const ushort8*)&xT[((size_t)b * HWN + p0 + row) * DIM + k0 + ko];
        __syncthreads();
        bf16x8 a0 = *(const bf16x8*)&ldsA[(mw + l15) * 40 + quad * 8];
        bf16x8 a1 = *(const bf16x8*)&ldsA[(mw + 16 + l15) * 40 + quad * 8];
        bf16x8 b0 = *(const bf16x8*)&ldsB[(nw + l15) * 40 + quad * 8];
        bf16x8 b1 = *(const bf16x8*)&ldsB[(nw + 16 + l15) * 40 + quad * 8];
        acc[0][0] = __builtin_amdgcn_mfma_f32_16x16x32_bf16(a0, b0, acc[0][0], 0, 0, 0);
        acc[0][1] = __builtin_amdgcn_mfma_f32_16x16x32_bf16(a0, b1, acc[0][1], 0, 0, 0);
        acc[1][0] = __builtin_amdgcn_mfma_f32_16x16x32_bf16(a1, b0, acc[1][0], 0, 0, 0);
        acc[1][1] = __builtin_amdgcn_mfma_f32_16x16x32_bf16(a1, b1, acc[1][1], 0, 0, 0);
        __syncthreads();
    }

    // transpose epilogue: cbuf[p][o] then coalesced row stores of Qt[b][p][o]
    #pragma unroll
    for (int mi = 0; mi < 2; ++mi)
        #pragma unroll
        for (int ni = 0; ni < 2; ++ni)
            #pragma unroll
            for (int r = 0; r < 4; ++r) {
                int m = mw + mi * 16 + quad * 4 + r;
                int n = nw + ni * 16 + l15;
                cbuf[n * 72 + m] = f2bf(acc[mi][ni][r] * 0.125f);
            }
    __syncthreads();
    {
        int n = tid >> 2, mo = (tid & 3) * 16;
        ushort8 v0 = *(const ushort8*)&cbuf[n * 72 + mo];
        ushort8 v1 = *(const ushort8*)&cbuf[n * 72 + mo + 8];
        ushort_t* dst = &qt[((size_t)b * HWN + p0 + n) * DIM + m0 + mo];
        *(ushort8*)&dst[0] = v0;
        *(ushort8*)&dst[8] = v1;
    }
}

// ---------------------------------------------------------------------------
// Kernel 2: KV conv-GEMM, k' = (q, c) ordering.
// o2 < 512  -> K bf16, Ks[b][h][j][d]      (transpose epilogue)
// o2 >= 512 -> V f16,  Vt[b][h][d][j]      (direct epilogue; f16 for the
//              16x16x16 f16 PV MFMA in attention)
// ---------------------------------------------------------------------------
__global__ __launch_bounds__(256) void kv_kernel(
        const ushort_t* __restrict__ xT, const ushort_t* __restrict__ wkvT,
        ushort_t* __restrict__ ks, _Float16* __restrict__ vt) {
    const int b  = blockIdx.z;
    const int m0 = blockIdx.y * 64;
    const int j0 = blockIdx.x * 64;

    __shared__ ushort_t ldsA[64 * 40];
    __shared__ ushort_t ldsB[64 * 40];
    __shared__ ushort_t cbuf[64 * 72];

    const int tid  = threadIdx.x;
    const int wave = tid >> 6;
    const int lane = tid & 63;
    const int l15  = lane & 15;
    const int quad = lane >> 4;
    const int mw   = (wave >> 1) * 32;
    const int nw   = (wave & 1) * 32;

    f32x4 zero = {0.f, 0.f, 0.f, 0.f};
    f32x4 acc[2][2] = {{zero, zero}, {zero, zero}};

    const int row = tid >> 2, ko = (tid & 3) * 8;
    const int yj = (j0 + row) >> 5, xj = (j0 + row) & 31;

    for (int k0 = 0; k0 < KKV; k0 += 32) {
        int q  = k0 >> 9;
        int c0 = k0 & 511;
        int di = q >> 1, dj = q & 1;
        int p  = (2 * yj + di) * 64 + 2 * xj + dj;
        *(ushort8*)&ldsA[row * 40 + ko] =
            *(const ushort8*)&wkvT[(size_t)(m0 + row) * KKV + k0 + ko];
        *(ushort8*)&ldsB[row * 40 + ko] =
            *(const ushort8*)&xT[((size_t)b * HWN + p) * DIM + c0 + ko];
        __syncthreads();
        bf16x8 a0 = *(const bf16x8*)&ldsA[(mw + l15) * 40 + quad * 8];
        bf16x8 a1 = *(const bf16x8*)&ldsA[(mw + 16 + l15) * 40 + quad * 8];
        bf16x8 b0 = *(const bf16x8*)&ldsB[(nw + l15) * 40 + quad * 8];
        bf16x8 b1 = *(const bf16x8*)&ldsB[(nw + 16 + l15) * 40 + quad * 8];
        acc[0][0] = __builtin_amdgcn_mfma_f32_16x16x32_bf16(a0, b0, acc[0][0], 0, 0, 0);
        acc[0][1] = __builtin_amdgcn_mfma_f32_16x16x32_bf16(a0, b1, acc[0][1], 0, 0, 0);
        acc[1][0] = __builtin_amdgcn_mfma_f32_16x16x32_bf16(a1, b0, acc[1][0], 0, 0, 0);
        acc[1][1] = __builtin_amdgcn_mfma_f32_16x16x32_bf16(a1, b1, acc[1][1], 0, 0, 0);
        __syncthreads();
    }

    if (m0 < DIM) {
        int h = m0 >> 6;
        #pragma unroll
        for (int mi = 0; mi < 2; ++mi)
            #pragma unroll
            for (int ni = 0; ni < 2; ++ni)
                #pragma unroll
                for (int r = 0; r < 4; ++r) {
                    int m = mw + mi * 16 + quad * 4 + r;
                    int n = nw + ni * 16 + l15;
                    cbuf[n * 72 + m] = f2bf(acc[mi][ni][r]);
                }
        __syncthreads();
        int n = tid >> 2, mo = (tid & 3) * 16;
        ushort8 v0 = *(const ushort8*)&cbuf[n * 72 + mo];
        ushort8 v1 = *(const ushort8*)&cbuf[n * 72 + mo + 8];
        ushort_t* dst = &ks[(((size_t)b * HEADS + h) * KVN + j0 + n) * HD + mo];
        *(ushort8*)&dst[0] = v0;
        *(ushort8*)&dst[8] = v1;
    } else {
        int h = (m0 - DIM) >> 6;
        #pragma unroll
        for (int mi = 0; mi < 2; ++mi)
            #pragma unroll
            for (int ni = 0; ni < 2; ++ni)
                #pragma unroll
                for (int r = 0; r < 4; ++r) {
                    int dd = mw + mi * 16 + quad * 4 + r;
                    int n  = nw + ni * 16 + l15;
                    vt[(((size_t)b * HEADS + h) * HD + dd) * KVN + j0 + n] =
                        (_Float16)acc[mi][ni][r];
                }
    }
}

// ---------------------------------------------------------------------------
// Kernel 3: attention v3 — zero LDS, zero barriers, zero shuffles.
// S^T = K Q^T via 16x16x32 bf16 MFMA; its C-layout (lane: j=quad*4+r,
// i=l15) IS the 16x16x16 A-frag layout (m=l15, k=quad*4+r), so
// P=exp(S^T) feeds PV (16x16x16 f16 MFMA, V stored f16) from registers.
// l via ones-MFMA lands row-aligned with O.  Wave = 32 queries.
// ---------------------------------------------------------------------------
__global__ __launch_bounds__(256) void attn_kernel(
        const ushort_t* __restrict__ qt,    // [b][p][c] bf16, pre-scaled 0.125
        const ushort_t* __restrict__ ks,    // [b][h][j][d] bf16
        const _Float16* __restrict__ vt,    // [b][h][d][j] f16
        ushort_t* __restrict__ ao) {        // [b][i][c] bf16
    const int b = blockIdx.z, h = blockIdx.y;
    const int tid = threadIdx.x, wave = tid >> 6, lane = tid & 63;
    const int l15 = lane & 15, quad = lane >> 4;
    const int iw = blockIdx.x * 128 + wave * 32;

    // Q B-fragments: B[k=d=quad*8+jj(+32)][n=i=l15], contiguous 16B loads
    bf16x8 bq[2][2];
    #pragma unroll
    for (int half = 0; half < 2; ++half) {
        const ushort_t* qrow =
            &qt[((size_t)b * HWN + iw + half * 16 + l15) * DIM + h * HD + quad * 8];
        bq[half][0] = *(const bf16x8*)&qrow[0];
        bq[half][1] = *(const bf16x8*)&qrow[32];
    }

    const ushort_t*  Kh = &ks[((size_t)b * HEADS + h) * (KVN * HD)];
    const _Float16*  Vh = &vt[((size_t)b * HEADS + h) * (HD * KVN)];

    f16x4 ones;
    ones[0] = (_Float16)1.0f; ones[1] = (_Float16)1.0f;
    ones[2] = (_Float16)1.0f; ones[3] = (_Float16)1.0f;

    f32x4 zero = {0.f, 0.f, 0.f, 0.f};
    f32x4 o[2][4] = {{zero, zero, zero, zero}, {zero, zero, zero, zero}};
    f32x4 ol[2] = {zero, zero};

    for (int jt = 0; jt < KVN; jt += 64) {
        // V B-frags (16x16x16): B[k=j=quad*4+jj][n=d=l15]; 8B loads from Vt
        f16x4 bv[4][4];   // [nt_j][nd]
        #pragma unroll
        for (int nd = 0; nd < 4; ++nd) {
            const _Float16* vrow = &Vh[(size_t)(nd * 16 + l15) * KVN + jt + quad * 4];
            #pragma unroll
            for (int nt = 0; nt < 4; ++nt)
                bv[nt][nd] = *(const f16x4*)&vrow[nt * 16];
        }
        // S^T tiles + exp + pack to f16 A-frags
        f16x4 ap[4][2];   // [nt_j][half_i]
        #pragma unroll
        for (int nt = 0; nt < 4; ++nt) {
            const ushort_t* krow = &Kh[(size_t)(jt + nt * 16 + l15) * HD + quad * 8];
            bf16x8 ak0 = *(const bf16x8*)&krow[0];
            bf16x8 ak1 = *(const bf16x8*)&krow[32];
            #pragma unroll
            for (int half = 0; half < 2; ++half) {
                f32x4 s = zero;
                s = __builtin_amdgcn_mfma_f32_16x16x32_bf16(ak0, bq[half][0], s, 0, 0, 0);
                s = __builtin_amdgcn_mfma_f32_16x16x32_bf16(ak1, bq[half][1], s, 0, 0, 0);
                float e0 = __builtin_amdgcn_exp2f(s[0] * LOG2E);
                float e1 = __builtin_amdgcn_exp2f(s[1] * LOG2E);
                float e2 = __builtin_amdgcn_exp2f(s[2] * LOG2E);
                float e3 = __builtin_amdgcn_exp2f(s[3] * LOG2E);
                union { f16x4 v4; struct { fp16x2 lo, hi; } p; } u;
                u.p.lo = __builtin_amdgcn_cvt_pkrtz(e0, e1);
                u.p.hi = __builtin_amdgcn_cvt_pkrtz(e2, e3);
                ap[nt][half] = u.v4;
            }
        }
        // O += P V,  l += P @ ones   (all register-resident)
        #pragma unroll
        for (int half = 0; half < 2; ++half) {
            #pragma unroll
            for (int nt = 0; nt < 4; ++nt) {
                ol[half] = __builtin_amdgcn_mfma_f32_16x16x16f16(ap[nt][half], ones, ol[half], 0, 0, 0);
                #pragma unroll
                for (int nd = 0; nd < 4; ++nd)
                    o[half][nd] = __builtin_amdgcn_mfma_f32_16x16x16f16(ap[nt][half], bv[nt][nd], o[half][nd], 0, 0, 0);
            }
        }
    }

    // epilogue: O/l share C-layout rows (i = quad*4+r); normalize and store
    #pragma unroll
    for (int half = 0; half < 2; ++half)
        #pragma unroll
        for (int r = 0; r < 4; ++r) {
            float invl = 1.0f / ol[half][r];
            int i = iw + half * 16 + quad * 4 + r;
            #pragma unroll
            for (int nd = 0; nd < 4; ++nd)
                ao[((size_t)b * HWN + i) * DIM + h * HD + nd * 16 + l15] =
                    f2bf(o[half][nd][r] * invl);
        }
}

// ---------------------------------------------------------------------------
// Kernel 4: output projection.  out[b][o][p] = sum_c Wout[o][c] * AO[b][p][c]
// ---------------------------------------------------------------------------
__global__ __launch_bounds__(256) void outproj_kernel(
        const ushort_t* __restrict__ ao, const ushort_t* __restrict__ woutb,
        float* __restrict__ out) {
    const int b  = blockIdx.z;
    const int m0 = blockIdx.y * 64;
    const int p0 = blockIdx.x * 64;

    __shared__ ushort_t ldsA[64 * 40];
    __shared__ ushort_t ldsB[64 * 40];

    const int tid  = threadIdx.x;
    const int wave = tid >> 6;
    const int lane = tid & 63;
    const int l15  = lane & 15;
    const int quad = lane >> 4;
    const int mw   = (wave >> 1) * 32;
    const int nw   = (wave & 1) * 32;

    f32x4 zero = {0.f, 0.f, 0.f, 0.f};
    f32x4 acc[2][2] = {{zero, zero}, {zero, zero}};

    for (int k0 = 0; k0 < DIM; k0 += 32) {
        int row = tid >> 2, ko = (tid & 3) * 8;
        *(ushort8*)&ldsA[row * 40 + ko] =
            *(const ushort8*)&woutb[(m0 + row) * DIM + k0 + ko];
        *(ushort8*)&ldsB[row * 40 + ko] =
            *(const ushort8*)&ao[((size_t)b * HWN + p0 + row) * DIM + k0 + ko];
        __syncthreads();
        bf16x8 a0 = *(const bf16x8*)&ldsA[(mw + l15) * 40 + quad * 8];
        bf16x8 a1 = *(const bf16x8*)&ldsA[(mw + 16 + l15) * 40 + quad * 8];
        bf16x8 b0 = *(const bf16x8*)&ldsB[(nw + l15) * 40 + quad * 8];
        bf16x8 b1 = *(const bf16x8*)&ldsB[(nw + 16 + l15) * 40 + quad * 8];
        acc[0][0] = __builtin_amdgcn_mfma_f32_16x16x32_bf16(a0, b0, acc[0][0], 0, 0, 0);
        acc[0][1] = __builtin_amdgcn_mfma_f32_16x16x32_bf16(a0, b1, acc[0][1], 0, 0, 0);
        acc[1][0] = __builtin_amdgcn_mfma_f32_16x16x32_bf16(a1, b0, acc[1][0], 0, 0, 0);
        acc[1][1] = __builtin_amdgcn_mfma_f32_16x16x32_bf16(a1, b1, acc[1][1], 0, 0, 0);
        __syncthreads();
    }

    #pragma unroll
    for (int mi = 0; mi < 2; ++mi)
        #pragma unroll
        for (int ni = 0; ni < 2; ++ni)
            #pragma unroll
            for (int r = 0; r < 4; ++r) {
                int m = m0 + mw + mi * 16 + quad * 4 + r;
                int n = p0 + nw + ni * 16 + l15;
                out[((size_t)b * DIM + m) * HWN + n] = acc[mi][ni][r];
            }
}

// ---------------------------------------------------------------------------
extern "C" void kernel_launch(void* const* d_in, const int* in_sizes, int n_in,
                              void* d_out, int out_size, void* d_ws, size_t ws_size,
                              hipStream_t stream) {
    const float* x    = (const float*)d_in[0];  // [4][512][64][64] f32
    const float* wq   = (const float*)d_in[1];  // [512][512] f32
    const float* wkv  = (const float*)d_in[2];  // [1024][512][2][2] f32
    const float* wout = (const float*)d_in[3];  // [512][512] f32
    float* out = (float*)d_out;                 // [4][512][64][64] f32

    char* ws = (char*)d_ws;
    ushort_t*  xT    = (ushort_t*)(ws);               // 16.78 MB  [b][p][c]
    ushort_t*  qtb   = (ushort_t*)(ws + 16777216);    // 16.78 MB  [b][p][c]
    ushort_t*  ksb   = (ushort_t*)(ws + 33554432);    //  4.19 MB  [b][h][j][d]
    _Float16*  vtb   = (_Float16*)(ws + 37748736);    //  4.19 MB  [b][h][d][j] f16
    ushort_t*  aob   = (ushort_t*)(ws + 41943040);    // 16.78 MB  [b][i][c]
    ushort_t*  wqb   = (ushort_t*)(ws + 58720256);    //  0.52 MB
    ushort_t*  wkvT  = (ushort_t*)(ws + 59244544);    //  4.19 MB  [o2][(q,c)]
    ushort_t*  woutb = (ushort_t*)(ws + 63438848);    //  0.52 MB

    cvt_xT_kernel  <<<dim3(64, 8, 4), 256, 0, stream>>>(x, xT);
    cvt_kernel     <<<dim3(128),      256, 0, stream>>>(wq, wqb, 32768);
    cvt_wkvT_kernel<<<dim3(2048),     256, 0, stream>>>(wkv, wkvT);
    cvt_kernel     <<<dim3(128),      256, 0, stream>>>(wout, woutb, 32768);

    qproj_kernel  <<<dim3(64, 8, 4),  256, 0, stream>>>(xT, wqb, qtb);
    kv_kernel     <<<dim3(16, 16, 4), 256, 0, stream>>>(xT, wkvT, ksb, vtb);
    attn_kernel   <<<dim3(32, 8, 4),  256, 0, stream>>>(qtb, ksb, vtb, aob);
    outproj_kernel<<<dim3(64, 8, 4),  256, 0, stream>>>(aob, woutb, out);
}